// Round 18
// baseline (820.499 us; speedup 1.0000x reference)
//
#include <hip/hip_runtime.h>
#include <hip/hip_bf16.h>

#define TOKENS 2048
#define HDIM   2560
#define NEXP   16
#define IDIM   1664
#define ISDIM  3328
#define NPAIR  (TOKENS*2)
#define NPERS  1024   // persistent blocks (4/CU x 256)

typedef float  f32x4   __attribute__((ext_vector_type(4)));
typedef __bf16 bf16x8  __attribute__((ext_vector_type(8)));
typedef short  short8v __attribute__((ext_vector_type(8)));

#define GLDS16(g, l) __builtin_amdgcn_global_load_lds( \
    (const __attribute__((address_space(1))) unsigned int*)(g), \
    (__attribute__((address_space(3))) unsigned int*)(l), 16, 0, 0)

#define VMCNT(n) asm volatile("s_waitcnt vmcnt(" #n ")" ::: "memory")
#define LGKM_BAR() do { \
    asm volatile("s_waitcnt lgkmcnt(0)" ::: "memory"); \
    __builtin_amdgcn_sched_barrier(0); \
    __builtin_amdgcn_s_barrier(); \
    __builtin_amdgcn_sched_barrier(0); \
  } while (0)

__device__ __forceinline__ short f2bf(float f) {
  unsigned u = __builtin_bit_cast(unsigned, f);
  u += 0x7FFFu + ((u >> 16) & 1u);          // RNE to bf16
  return (short)(u >> 16);
}

// ---------------- router: fp32 logits, softmax-top2-renorm == sigmoid(l0-l1)
__global__ void router_kernel(const float* __restrict__ x, const float* __restrict__ rw,
                              int* __restrict__ counts, int* __restrict__ tidx,
                              float* __restrict__ tw) {
  const int t = blockIdx.x;
  const int lane = threadIdx.x;
  float acc[NEXP];
#pragma unroll
  for (int e = 0; e < NEXP; ++e) acc[e] = 0.f;
  const float* xr = x + (size_t)t * HDIM;
  for (int k = lane; k < HDIM; k += 64) {
    float xv = xr[k];
#pragma unroll
    for (int e = 0; e < NEXP; ++e) acc[e] += xv * rw[e * HDIM + k];
  }
#pragma unroll
  for (int e = 0; e < NEXP; ++e) {
#pragma unroll
    for (int o = 32; o > 0; o >>= 1) acc[e] += __shfl_down(acc[e], o);
  }
  if (lane == 0) {
    int i0 = 0; float v0 = acc[0];
#pragma unroll
    for (int e = 1; e < NEXP; ++e) if (acc[e] > v0) { v0 = acc[e]; i0 = e; }
    int i1 = -1; float v1 = -3.4e38f;
#pragma unroll
    for (int e = 0; e < NEXP; ++e) if (e != i0 && acc[e] > v1) { v1 = acc[e]; i1 = e; }
    float w0 = 1.f / (1.f + expf(v1 - v0));
    tidx[t * 2] = i0; tidx[t * 2 + 1] = i1;
    tw[t * 2] = w0;   tw[t * 2 + 1] = 1.f - w0;
    atomicAdd(&counts[i0], 1);
    atomicAdd(&counts[i1], 1);
  }
}

// scan + tile-queue metadata: meta[0..15]=panel prefix, meta[16]=total panels
__global__ void scan_kernel(const int* __restrict__ counts, int* __restrict__ offsets,
                            int* __restrict__ meta) {
  if (threadIdx.x == 0) {
    int a = 0, p = 0;
    for (int e = 0; e < NEXP; ++e) {
      offsets[e] = a;
      meta[e] = p;
      a += counts[e];
      p += (counts[e] + 127) >> 7;     // ceil(cnt/128) panels
    }
    meta[16] = p;
  }
}

// ---------------- bucket pairs + gather bf16 activations
__global__ void gather_kernel(const float* __restrict__ x, const int* __restrict__ tidx,
                              const float* __restrict__ tw, const int* __restrict__ offsets,
                              int* __restrict__ slotc, int* __restrict__ pairpos,
                              float* __restrict__ wrow, short* __restrict__ xb,
                              short* __restrict__ xg) {
  const int t = blockIdx.x, tid = threadIdx.x;
  __shared__ int grs[2];
  if (tid < 2) {
    int e = tidx[t * 2 + tid];
    int slot = atomicAdd(&slotc[e], 1);
    int g = offsets[e] + slot;
    grs[tid] = g;
    pairpos[t * 2 + tid] = g;
    wrow[g] = tw[t * 2 + tid];
  }
  __syncthreads();
  const int g0 = grs[0], g1 = grs[1];
  const float* xr = x + (size_t)t * HDIM;
#pragma unroll
  for (int i = 0; i < HDIM / 256; ++i) {
    int k = tid + i * 256;
    short v = f2bf(xr[k]);
    xb[(size_t)t * HDIM + k] = v;
    xg[(size_t)g0 * HDIM + k] = v;
    xg[(size_t)g1 * HDIM + k] = v;
  }
}

// ---- conv4: 4 k-tiles (32k x BN each) fp32 -> bf16 tile-linear pre-swizzled,
// LDS stride BN+1, register prefetch of tile kt+1 during convert of kt.
template <int BN>
__device__ __forceinline__ void conv4(const float* __restrict__ sbase,
                                      short* __restrict__ dbase,
                                      const int N, const int kt0,
                                      const int tid, float* __restrict__ lds) {
  constexpr int NL = BN / 32;               // f32x4 loads per thread
  f32x4 cur[NL], nxt[NL];
#pragma unroll
  for (int c = 0; c < NL; ++c) {
    const int f = tid * (BN / 8) + c * 4;
    cur[c] = *reinterpret_cast<const f32x4*>(
        sbase + (size_t)(kt0 * 32 + f / BN) * N + (f % BN));
  }
#pragma unroll
  for (int k4 = 0; k4 < 4; ++k4) {
    const int kt = kt0 + k4;
#pragma unroll
    for (int c = 0; c < NL; ++c) {
      const int f = tid * (BN / 8) + c * 4;
      *reinterpret_cast<f32x4*>(lds + (f / BN) * (BN + 1) + (f % BN)) = cur[c];
    }
    __syncthreads();
    if (k4 < 3) {
#pragma unroll
      for (int c = 0; c < NL; ++c) {
        const int f = tid * (BN / 8) + c * 4;
        nxt[c] = *reinterpret_cast<const f32x4*>(
            sbase + (size_t)((kt + 1) * 32 + f / BN) * N + (f % BN));
      }
    }
    short* d = dbase + (size_t)kt * BN * 32;
#pragma unroll
    for (int q = 0; q < BN / 64; ++q) {
      const int uidx = tid + q * 256;
      const int n = uidx >> 2, u = uidx & 3;
      const int koct = u ^ ((n >> 1) & 3);
      short8v o;
#pragma unroll
      for (int j = 0; j < 8; ++j) o[j] = f2bf(lds[(koct * 8 + j) * (BN + 1) + n]);
      *reinterpret_cast<short8v*>(d + uidx * 8) = o;
    }
    __syncthreads();
#pragma unroll
    for (int c = 0; c < NL; ++c) cur[c] = nxt[c];
  }
}

// ---------------- merged up-phase weight convert: w1|w3|sg|su in ONE dispatch
__global__ void wconv_up_kernel(const float* __restrict__ w1, const float* __restrict__ w3,
                                const float* __restrict__ sg, const float* __restrict__ su,
                                short* __restrict__ cwA, short* __restrict__ cwB,
                                short* __restrict__ cwS1, short* __restrict__ cwS2) {
  __shared__ float lds[32 * 65];
  const int b = blockIdx.x;
  const float* src; short* dst; int N, nt, slab, kc;
  if (b < 8320) {                       // w1: 16 slabs x 26 nt x 20 kc
    kc = b % 20; int r = b / 20; nt = r % 26; slab = r / 26;
    src = w1; dst = cwA; N = IDIM;
  } else if (b < 16640) {
    const int i = b - 8320;
    kc = i % 20; int r = i / 20; nt = r % 26; slab = r / 26;
    src = w3; dst = cwB; N = IDIM;
  } else if (b < 17680) {
    const int i = b - 16640;
    kc = i % 20; nt = i / 20; slab = 0;
    src = sg; dst = cwS1; N = ISDIM;
  } else {
    const int i = b - 17680;
    kc = i % 20; nt = i / 20; slab = 0;
    src = su; dst = cwS2; N = ISDIM;
  }
  const int nT = (N == IDIM) ? 26 : 52;
  const float* sbase = src + (size_t)slab * HDIM * N + nt * 64;
  short* dbase = dst + ((size_t)((slab * nT + nt) * 80)) * 2048;
  conv4<64>(sbase, dbase, N, kc * 4, threadIdx.x, lds);
}

// ---------------- merged dn-phase weight convert: w2|sd in ONE dispatch
__global__ void wconv_dn_kernel(const float* __restrict__ w2, const float* __restrict__ sd,
                                short* __restrict__ cw2, short* __restrict__ csd) {
  __shared__ float lds[32 * 129];
  const int b = blockIdx.x;
  if (b < 4160) {                       // w2: 16 slabs x 20 nt x 13 kc
    const int kc = b % 13; int r = b / 13; const int nt = r % 20; const int slab = r / 20;
    const float* sbase = w2 + (size_t)slab * IDIM * HDIM + nt * 128;
    short* dbase = cw2 + ((size_t)((slab * 20 + nt) * 52)) * 4096;
    conv4<128>(sbase, dbase, HDIM, kc * 4, threadIdx.x, lds);
  } else {                              // sd: 20 nt x 26 kc
    const int i = b - 4160;
    const int kc = i % 26; const int nt = i / 26;
    const float* sbase = sd + nt * 128;
    short* dbase = csd + ((size_t)(nt * 104)) * 4096;
    conv4<128>(sbase, dbase, HDIM, kc * 4, threadIdx.x, lds);
  }
}

// ================= merged UP (persistent, 256 thr = 4 waves):
// H = bf16( silu(A*B1) * (A*B3) ).  Block tile 128m x 64n x {G,U}.
// Wave w: m-half (w&1), mat (w>>1); wave tile 64x64.
// A depth-2 + B depth-3 = 40KB LDS -> 4 blocks/CU (16 waves).  VMCNT(2) at
// the barrier leaves the newest B pair in flight (B ~2-step budget).
__launch_bounds__(256, 4)
__global__ void moe_up_k(const short* __restrict__ xg, const short* __restrict__ xb,
                         const short* __restrict__ cw1, const short* __restrict__ cw3,
                         const short* __restrict__ csg, const short* __restrict__ csu,
                         short* __restrict__ hbE, short* __restrict__ hbS,
                         const int* __restrict__ counts, const int* __restrict__ offsets,
                         const int* __restrict__ meta) {
  const int tid = threadIdx.x;
  __shared__ int spre[17];
  __shared__ __align__(16) char pool[40960];
  short (*Ab)[128][32] = (short(*)[128][32])pool;             // [2][128][32]  16KB
  short (*Bb)[128][32] = (short(*)[128][32])(pool + 16384);   // [3][G64|U64][32] 24KB
  float* scratch = (float*)pool;                              // 32KB, epilogue only

  if (tid < 17) spre[tid] = meta[tid];
  __syncthreads();
  const int gemmE = spre[16] * 26;
  const int total = gemmE + 832;

  const int lane = tid & 63;
  const int w = tid >> 6;
  const int wmv = (w & 1) * 64;     // m-half
  const int mat = w >> 1;           // 0=G, 1=U
  const int lrow = lane & 15;
  const int lkg = lane >> 4;
  const int a_ko = (tid & 3) << 3;

  for (int ticket = blockIdx.x; ticket < total; ticket += NPERS) {
    const short* A; const short* b1tile; const short* b3tile; short* H;
    int N, mtile, ntile, rowbase = 0, cnt = 0x7fffffff;
    bool expert;
    if (ticket < gemmE) {
      const int p = ticket / 26;
      const int n = ticket % 26;
      int e = 0;
#pragma unroll
      for (int i = 1; i < 16; ++i) if (p >= spre[i]) e = i;
      const int m = p - spre[e];
      cnt = counts[e];
      rowbase = offsets[e];
      mtile = m * 128;
      A = xg;
      b1tile = cw1 + ((size_t)((e * 26 + n) * 80)) * 2048;
      b3tile = cw3 + ((size_t)((e * 26 + n) * 80)) * 2048;
      H = hbE; N = IDIM; ntile = n * 64; expert = true;
    } else {
      const int s = ticket - gemmE;   // 0..831
      const int n = s % 52;
      const int m = s / 52;           // 0..15
      mtile = m * 128;
      A = xb;
      b1tile = csg + ((size_t)(n * 80)) * 2048;
      b3tile = csu + ((size_t)(n * 80)) * 2048;
      H = hbS; N = ISDIM; ntile = n * 64; expert = false;
    }
    const int K = HDIM;
    const int KT = HDIM / 32;         // 80

    f32x4 acc[4][4];
#pragma unroll
    for (int i = 0; i < 4; ++i)
#pragma unroll
      for (int j = 0; j < 4; ++j) { f32x4 z = {0.f,0.f,0.f,0.f}; acc[i][j] = z; }

    int gr0, gr1;
    {
      int r0 = tid >> 2, r1 = (tid >> 2) + 64;
      gr0 = expert ? (rowbase + mtile + r0) : (mtile + r0);
      gr1 = expert ? (rowbase + mtile + r1) : (mtile + r1);
      if (gr0 > NPAIR - 1) gr0 = NPAIR - 1;
      if (gr1 > NPAIR - 1) gr1 = NPAIR - 1;
    }
    const short* a_src0 = A + (size_t)gr0 * K + a_ko;
    const short* a_src1 = A + (size_t)gr1 * K + a_ko;

#define STAGEA_U(kt) do { \
    GLDS16(a_src0 + ((kt) << 5), (short*)Ab[(kt) & 1] + tid * 8); \
    GLDS16(a_src1 + ((kt) << 5), (short*)Ab[(kt) & 1] + (tid + 256) * 8); \
  } while (0)
#define STAGEB_U(kt) do { \
    GLDS16(b1tile + (size_t)(kt) * 2048 + tid * 8, (short*)Bb[(kt) % 3] + tid * 8); \
    GLDS16(b3tile + (size_t)(kt) * 2048 + tid * 8, (short*)Bb[(kt) % 3] + 2048 + tid * 8); \
  } while (0)

    auto compute = [&](int ab, int bb) {
      bf16x8 af[4], bfv[4];
#pragma unroll
      for (int mf = 0; mf < 4; ++mf)
        af[mf] = *reinterpret_cast<const bf16x8*>(&Ab[ab][wmv + mf * 16 + lrow][lkg << 3]);
#pragma unroll
      for (int nf = 0; nf < 4; ++nf) {
        const int nloc = nf * 16 + lrow;
        const int kg = (lkg ^ ((nloc >> 1) & 3)) << 3;
        bfv[nf] = *reinterpret_cast<const bf16x8*>(&Bb[bb][mat * 64 + nloc][kg]);
      }
      __builtin_amdgcn_s_setprio(1);
#pragma unroll
      for (int mf = 0; mf < 4; ++mf)
#pragma unroll
        for (int nf = 0; nf < 4; ++nf)
          acc[mf][nf] = __builtin_amdgcn_mfma_f32_16x16x32_bf16(af[mf], bfv[nf], acc[mf][nf], 0, 0, 0);
      __builtin_amdgcn_s_setprio(0);
    };

    // prologue: A(0), B(0), B(1); wait for A(0),B(0) -> VMCNT(2)
    STAGEA_U(0);
    STAGEB_U(0); STAGEB_U(1);
    VMCNT(2);
    LGKM_BAR();
    for (int i = 0; i < KT; ++i) {
      if (i) {
        if (i + 1 < KT) { VMCNT(2); } else { VMCNT(0); }
        LGKM_BAR();
      }
      if (i + 1 < KT) STAGEA_U(i + 1);
      if (i + 2 < KT) STAGEB_U(i + 2);
      compute(i & 1, i % 3);
    }
    LGKM_BAR();   // all compute reads done before scratch writes

    // epilogue: U-waves export acc to scratch; G-waves fuse silu(g)*u -> H.
    if (mat) {
      float* sc = scratch + (size_t)(w & 1) * 4096;
#pragma unroll
      for (int mf = 0; mf < 4; ++mf)
#pragma unroll
        for (int r = 0; r < 4; ++r) {
          const int row = mf * 16 + ((lane >> 4) << 2) + r;
#pragma unroll
          for (int nf = 0; nf < 4; ++nf)
            sc[row * 64 + nf * 16 + lrow] = acc[mf][nf][r];
        }
    }
    LGKM_BAR();
    if (!mat) {
      const float* sc = scratch + (size_t)(w & 1) * 4096;
#pragma unroll
      for (int mf = 0; mf < 4; ++mf) {
#pragma unroll
        for (int r = 0; r < 4; ++r) {
          const int row = mf * 16 + ((lane >> 4) << 2) + r;
          const int rt = wmv + row;
          if (expert && mtile + rt >= cnt) continue;
          const size_t grow = (size_t)((expert ? rowbase : 0) + mtile + rt);
          const int colb = ntile + lrow;
#pragma unroll
          for (int nf = 0; nf < 4; ++nf) {
            float g = acc[mf][nf][r];
            float u = sc[row * 64 + nf * 16 + lrow];
            H[grow * N + colb + nf * 16] = f2bf(g / (1.f + expf(-g)) * u);
          }
        }
      }
    }
    LGKM_BAR();   // scratch reads complete before next ticket's staging
#undef STAGEA_U
#undef STAGEB_U
  }
}

// ================= merged DOWN (persistent, 256 thr = 4 waves): Out = A*B.
// Block tile 128m x 128n; wave tile 64x64.  A depth-2 + B depth-3 = 40KB.
// Shared tiles (KT=104) ticketed FIRST so long tiles never start in the tail.
__launch_bounds__(256, 4)
__global__ void moe_dn_k(const short* __restrict__ hbE, const short* __restrict__ hbS,
                         const short* __restrict__ cw2, const short* __restrict__ csd,
                         float* __restrict__ pairs, float* __restrict__ outb,
                         const int* __restrict__ counts, const int* __restrict__ offsets,
                         const float* __restrict__ wrow, const int* __restrict__ meta) {
  const int tid = threadIdx.x;
  __shared__ int spre[17];
  __shared__ short Ab[2][128][32];   // 16 KB, linear
  __shared__ short Bb[3][128][32];   // 24 KB, swizzled [n][k] tile-linear

  if (tid < 17) spre[tid] = meta[tid];
  __syncthreads();
  const int total = spre[16] * 20 + 320;

  const int lane = tid & 63;
  const int w = tid >> 6;
  const int wm = (w >> 1) * 64;
  const int wn = (w & 1) * 64;
  const int lrow = lane & 15;
  const int lkg = lane >> 4;
  const int a_ko = (tid & 3) << 3;

  for (int ticket = blockIdx.x; ticket < total; ticket += NPERS) {
    const short* A; const short* btile; float* Out;
    int K, KT, mtile, ntile, rowbase = 0, cnt = 0x7fffffff;
    bool expert;
    if (ticket < 320) {               // shared first (long tiles)
      const int n = ticket % 20;
      const int m = ticket / 20;      // 0..15
      mtile = m * 128;
      A = hbS;
      btile = csd + ((size_t)(n * 104)) * 4096;
      Out = outb; K = ISDIM; KT = ISDIM / 32; ntile = n * 128; expert = false; // KT=104
    } else {
      const int te = ticket - 320;
      const int p = te / 20;
      const int n = te % 20;
      int e = 0;
#pragma unroll
      for (int i = 1; i < 16; ++i) if (p >= spre[i]) e = i;
      const int m = p - spre[e];
      cnt = counts[e];
      rowbase = offsets[e];
      mtile = m * 128;
      A = hbE;
      btile = cw2 + ((size_t)((e * 20 + n) * 52)) * 4096;
      Out = pairs; K = IDIM; KT = IDIM / 32; ntile = n * 128; expert = true;   // KT=52
    }

    f32x4 acc[4][4];
#pragma unroll
    for (int i = 0; i < 4; ++i)
#pragma unroll
      for (int j = 0; j < 4; ++j) { f32x4 z = {0.f,0.f,0.f,0.f}; acc[i][j] = z; }

    int gr0, gr1;
    {
      int r0 = tid >> 2, r1 = (tid >> 2) + 64;
      gr0 = expert ? (rowbase + mtile + r0) : (mtile + r0);
      gr1 = expert ? (rowbase + mtile + r1) : (mtile + r1);
      if (gr0 > NPAIR - 1) gr0 = NPAIR - 1;
      if (gr1 > NPAIR - 1) gr1 = NPAIR - 1;
    }
    const short* a_src0 = A + (size_t)gr0 * K + a_ko;
    const short* a_src1 = A + (size_t)gr1 * K + a_ko;

#define STAGEA_D(kt) do { \
    GLDS16(a_src0 + ((kt) << 5), (short*)Ab[(kt) & 1] + tid * 8); \
    GLDS16(a_src1 + ((kt) << 5), (short*)Ab[(kt) & 1] + (tid + 256) * 8); \
  } while (0)
#define STAGEB_D(kt) do { \
    GLDS16(btile + (size_t)(kt) * 4096 + tid * 8, (short*)Bb[(kt) % 3] + tid * 8); \
    GLDS16(btile + (size_t)(kt) * 4096 + (tid + 256) * 8, (short*)Bb[(kt) % 3] + (tid + 256) * 8); \
  } while (0)

    auto compute = [&](int ab, int bb) {
      bf16x8 af[4], bfv[4];
#pragma unroll
      for (int mf = 0; mf < 4; ++mf)
        af[mf] = *reinterpret_cast<const bf16x8*>(&Ab[ab][wm + mf * 16 + lrow][lkg << 3]);
#pragma unroll
      for (int nf = 0; nf < 4; ++nf) {
        const int n = wn + nf * 16 + lrow;
        const int kg = (lkg ^ ((n >> 1) & 3)) << 3;
        bfv[nf] = *reinterpret_cast<const bf16x8*>(&Bb[bb][n][kg]);
      }
      __builtin_amdgcn_s_setprio(1);
#pragma unroll
      for (int mf = 0; mf < 4; ++mf)
#pragma unroll
        for (int nf = 0; nf < 4; ++nf)
          acc[mf][nf] = __builtin_amdgcn_mfma_f32_16x16x32_bf16(af[mf], bfv[nf], acc[mf][nf], 0, 0, 0);
      __builtin_amdgcn_s_setprio(0);
    };

    STAGEA_D(0);
    STAGEB_D(0); STAGEB_D(1);
    VMCNT(2);
    LGKM_BAR();
    for (int i = 0; i < KT; ++i) {
      if (i) {
        if (i + 1 < KT) { VMCNT(2); } else { VMCNT(0); }
        LGKM_BAR();
      }
      if (i + 1 < KT) STAGEA_D(i + 1);
      if (i + 2 < KT) STAGEB_D(i + 2);
      compute(i & 1, i % 3);
    }

#pragma unroll
    for (int mf = 0; mf < 4; ++mf) {
#pragma unroll
      for (int r = 0; r < 4; ++r) {
        const int rt = wm + mf * 16 + ((lane >> 4) << 2) + r;
        const int colb = ntile + wn + lrow;
        if (expert) {
          if (mtile + rt < cnt) {
            const int gr = rowbase + mtile + rt;
            const float sc = wrow[gr];
            float* o = Out + (size_t)gr * HDIM + colb;
#pragma unroll
            for (int nf = 0; nf < 4; ++nf) o[nf * 16] = sc * acc[mf][nf][r];
          }
        } else {
          float* o = Out + (size_t)(mtile + rt) * HDIM + colb;
#pragma unroll
          for (int nf = 0; nf < 4; ++nf) o[nf * 16] = acc[mf][nf][r];
        }
      }
    }
    LGKM_BAR();   // final compute reads complete before next ticket's staging
#undef STAGEA_D
#undef STAGEB_D
  }
}

// ---------------- final combine: out[t] += pairs[g0] + pairs[g1]
__global__ void combine_kernel(float* __restrict__ out, const float* __restrict__ pairs,
                               const int* __restrict__ pairpos) {
  const int t = blockIdx.x;
  const int g0 = pairpos[t * 2], g1 = pairpos[t * 2 + 1];
  const f32x4* p0 = (const f32x4*)(pairs + (size_t)g0 * HDIM);
  const f32x4* p1 = (const f32x4*)(pairs + (size_t)g1 * HDIM);
  f32x4* o = (f32x4*)(out + (size_t)t * HDIM);
  for (int c = threadIdx.x; c < HDIM / 4; c += 256)
    o[c] = o[c] + p0[c] + p1[c];
}

extern "C" void kernel_launch(void* const* d_in, const int* in_sizes, int n_in,
                              void* d_out, int out_size, void* d_ws, size_t ws_size,
                              hipStream_t stream) {
  const float* x  = (const float*)d_in[0];
  const float* rw = (const float*)d_in[1];
  const float* w1 = (const float*)d_in[2];
  const float* w3 = (const float*)d_in[3];
  const float* w2 = (const float*)d_in[4];
  const float* sg = (const float*)d_in[5];
  const float* su = (const float*)d_in[6];
  const float* sd = (const float*)d_in[7];
  float* out = (float*)d_out;
  (void)in_sizes; (void)n_in; (void)out_size; (void)ws_size;

  char* ws = (char*)d_ws;
  size_t off = 0;
  auto alloc = [&](size_t bytes) -> void* {
    void* p = ws + off;
    off = (off + bytes + 255) & ~(size_t)255;
    return p;
  };
  int*   counts  = (int*)alloc(NEXP * 4);          // @0
  int*   slotc   = (int*)alloc(NEXP * 4);          // @256
  int*   offsets = (int*)alloc(NEXP * 4);
  int*   meta    = (int*)alloc(32 * 4);
  int*   tidx    = (int*)alloc(NPAIR * 4);
  float* tw      = (float*)alloc(NPAIR * 4);
  float* wrowv   = (float*)alloc(NPAIR * 4);
  int*   pairpos = (int*)alloc(NPAIR * 4);
  short* xb      = (short*)alloc((size_t)TOKENS * HDIM * 2);
  short* xg      = (short*)alloc((size_t)NPAIR * HDIM * 2);
  short* hbE     = (short*)alloc((size_t)NPAIR * IDIM * 2);
  short* hbS     = (short*)alloc((size_t)TOKENS * ISDIM * 2);
  float* pairs   = (float*)alloc((size_t)NPAIR * HDIM * 4);
  // converted-weight regions (phase-reused): cwA holds w1' then w2'; cwS1 sg' then sd'
  short* cwA  = (short*)alloc((size_t)NEXP * HDIM * IDIM * 2);   // 136.3 MB
  short* cwB  = (short*)alloc((size_t)NEXP * HDIM * IDIM * 2);   // 136.3 MB
  short* cwS1 = (short*)alloc((size_t)HDIM * ISDIM * 2);         // 17.0 MB
  short* cwS2 = (short*)alloc((size_t)HDIM * ISDIM * 2);         // 17.0 MB

  hipMemsetAsync(d_ws, 0, 512, stream);  // zero counts + slotc

  router_kernel<<<dim3(TOKENS), dim3(64), 0, stream>>>(x, rw, counts, tidx, tw);
  scan_kernel<<<dim3(1), dim3(64), 0, stream>>>(counts, offsets, meta);
  gather_kernel<<<dim3(TOKENS), dim3(256), 0, stream>>>(x, tidx, tw, offsets, slotc,
                                                        pairpos, wrowv, xb, xg);

  // convert up-phase weights: single merged dispatch (w1|w3|sg|su)
  wconv_up_kernel<<<dim3(18720), dim3(256), 0, stream>>>(w1, w3, sg, su,
                                                         cwA, cwB, cwS1, cwS2);

  // merged up: persistent 1024 blocks over compact ticket space
  moe_up_k<<<dim3(NPERS), dim3(256), 0, stream>>>(
      xg, xb, cwA, cwB, cwS1, cwS2, hbE, hbS, counts, offsets, meta);

  // convert down-phase weights: single merged dispatch (w2|sd)
  wconv_dn_kernel<<<dim3(4680), dim3(256), 0, stream>>>(w2, sd, cwA, cwS1);

  // merged down: persistent 1024 blocks
  moe_dn_k<<<dim3(NPERS), dim3(256), 0, stream>>>(
      hbE, hbS, cwA, cwS1, pairs, out, counts, offsets, wrowv, meta);

  combine_kernel<<<dim3(TOKENS), dim3(256), 0, stream>>>(out, pairs, pairpos);
}

// Round 19
// 780.780 us; speedup vs baseline: 1.0509x; 1.0509x over previous
//
#include <hip/hip_runtime.h>
#include <hip/hip_bf16.h>

#define TOKENS 2048
#define HDIM   2560
#define NEXP   16
#define IDIM   1664
#define ISDIM  3328
#define NPAIR  (TOKENS*2)
#define NPERS  768    // persistent blocks: 8 XCD chunks x 96

typedef float  f32x4   __attribute__((ext_vector_type(4)));
typedef __bf16 bf16x8  __attribute__((ext_vector_type(8)));
typedef short  short8v __attribute__((ext_vector_type(8)));

#define GLDS16(g, l) __builtin_amdgcn_global_load_lds( \
    (const __attribute__((address_space(1))) unsigned int*)(g), \
    (__attribute__((address_space(3))) unsigned int*)(l), 16, 0, 0)

#define VMCNT(n) asm volatile("s_waitcnt vmcnt(" #n ")" ::: "memory")
#define LGKM_BAR() do { \
    asm volatile("s_waitcnt lgkmcnt(0)" ::: "memory"); \
    __builtin_amdgcn_sched_barrier(0); \
    __builtin_amdgcn_s_barrier(); \
    __builtin_amdgcn_sched_barrier(0); \
  } while (0)

__device__ __forceinline__ short f2bf(float f) {
  unsigned u = __builtin_bit_cast(unsigned, f);
  u += 0x7FFFu + ((u >> 16) & 1u);          // RNE to bf16
  return (short)(u >> 16);
}

// ---- coalesced conv-tile: 32k x BN fp32 (N-contig rows) -> bf16 tile-linear,
// pre-swizzled (unit u = n*4 + (koct ^ ((n>>1)&3)), byte j = k&7).
template <int BN>
__device__ __forceinline__ void conv_tile(const float* __restrict__ src,
                                          short* __restrict__ dst,
                                          const int N, const int tid,
                                          float* __restrict__ lds) {
  const int FPT = BN / 8;                    // floats per thread (8 or 16)
#pragma unroll
  for (int c4 = 0; c4 < FPT / 4; ++c4) {
    const int f = tid * FPT + c4 * 4;
    const int row = f / BN, col = f % BN;
    f32x4 v = *reinterpret_cast<const f32x4*>(src + (size_t)row * N + col);
    *reinterpret_cast<f32x4*>(lds + row * (BN + 4) + col) = v;
  }
  __syncthreads();
#pragma unroll
  for (int q = 0; q < BN / 64; ++q) {
    const int uidx = tid + q * 256;
    const int n = uidx >> 2, u = uidx & 3;
    const int koct = u ^ ((n >> 1) & 3);
    short8v o;
#pragma unroll
    for (int j = 0; j < 8; ++j) o[j] = f2bf(lds[(koct * 8 + j) * (BN + 4) + n]);
    *reinterpret_cast<short8v*>(dst + uidx * 8) = o;
  }
  __syncthreads();
}

// ---------------- router: fp32 logits, softmax-top2-renorm == sigmoid(l0-l1)
__global__ void router_kernel(const float* __restrict__ x, const float* __restrict__ rw,
                              int* __restrict__ counts, int* __restrict__ tidx,
                              float* __restrict__ tw) {
  const int t = blockIdx.x;
  const int lane = threadIdx.x;
  float acc[NEXP];
#pragma unroll
  for (int e = 0; e < NEXP; ++e) acc[e] = 0.f;
  const float* xr = x + (size_t)t * HDIM;
  for (int k = lane; k < HDIM; k += 64) {
    float xv = xr[k];
#pragma unroll
    for (int e = 0; e < NEXP; ++e) acc[e] += xv * rw[e * HDIM + k];
  }
#pragma unroll
  for (int e = 0; e < NEXP; ++e) {
#pragma unroll
    for (int o = 32; o > 0; o >>= 1) acc[e] += __shfl_down(acc[e], o);
  }
  if (lane == 0) {
    int i0 = 0; float v0 = acc[0];
#pragma unroll
    for (int e = 1; e < NEXP; ++e) if (acc[e] > v0) { v0 = acc[e]; i0 = e; }
    int i1 = -1; float v1 = -3.4e38f;
#pragma unroll
    for (int e = 0; e < NEXP; ++e) if (e != i0 && acc[e] > v1) { v1 = acc[e]; i1 = e; }
    float w0 = 1.f / (1.f + expf(v1 - v0));
    tidx[t * 2] = i0; tidx[t * 2 + 1] = i1;
    tw[t * 2] = w0;   tw[t * 2 + 1] = 1.f - w0;
    atomicAdd(&counts[i0], 1);
    atomicAdd(&counts[i1], 1);
  }
}

// scan + tile-queue metadata: meta[0..15]=panel prefix, meta[16]=total panels
__global__ void scan_kernel(const int* __restrict__ counts, int* __restrict__ offsets,
                            int* __restrict__ meta) {
  if (threadIdx.x == 0) {
    int a = 0, p = 0;
    for (int e = 0; e < NEXP; ++e) {
      offsets[e] = a;
      meta[e] = p;
      a += counts[e];
      p += (counts[e] + 127) >> 7;     // ceil(cnt/128) panels
    }
    meta[16] = p;
  }
}

// ---------------- bucket pairs + gather bf16 activations
__global__ void gather_kernel(const float* __restrict__ x, const int* __restrict__ tidx,
                              const float* __restrict__ tw, const int* __restrict__ offsets,
                              int* __restrict__ slotc, int* __restrict__ pairpos,
                              float* __restrict__ wrow, short* __restrict__ xb,
                              short* __restrict__ xg) {
  const int t = blockIdx.x, tid = threadIdx.x;
  __shared__ int grs[2];
  if (tid < 2) {
    int e = tidx[t * 2 + tid];
    int slot = atomicAdd(&slotc[e], 1);
    int g = offsets[e] + slot;
    grs[tid] = g;
    pairpos[t * 2 + tid] = g;
    wrow[g] = tw[t * 2 + tid];
  }
  __syncthreads();
  const int g0 = grs[0], g1 = grs[1];
  const float* xr = x + (size_t)t * HDIM;
#pragma unroll
  for (int i = 0; i < HDIM / 256; ++i) {
    int k = tid + i * 256;
    short v = f2bf(xr[k]);
    xb[(size_t)t * HDIM + k] = v;
    xg[(size_t)g0 * HDIM + k] = v;
    xg[(size_t)g1 * HDIM + k] = v;
  }
}

// ---------------- standalone coalesced weight convert (one tile per block)
template <int BN>
__global__ void wconv2_kernel(const float* __restrict__ src, short* __restrict__ dst,
                              const int K, const int N, const int nT, const int kT) {
  __shared__ float lds[32 * (BN + 4)];
  int b = blockIdx.x;
  const int kt = b % kT;
  b /= kT;
  const int nt = b % nT;
  const int slab = b / nT;
  const float* s = src + (size_t)slab * K * N + (size_t)(kt * 32) * N + nt * BN;
  short* d = dst + ((size_t)((slab * nT + nt) * kT + kt)) * BN * 32;
  conv_tile<BN>(s, d, N, threadIdx.x, lds);
}

// ================= merged UP (persistent, 256 thr = 4 waves):
// H = bf16( silu(A*B1) * (A*B3) ).  Block tile 128m x 64n x {G,U}.
// Wave w: m-half (w&1), mat (w>>1); wave tile 64x64.
// Asymmetric depth (A 2, B 4), VMCNT(2) at barrier (R16-best config).
// XCD-chunked tickets: block b -> (xcd=b&7, lane=b>>3); each XCD owns a
// contiguous expert-ticket chunk (+exact 1/8 of shared) -> A panels L2-local.
__launch_bounds__(256, 3)
__global__ void moe_up_k(const short* __restrict__ xg, const short* __restrict__ xb,
                         const short* __restrict__ cw1, const short* __restrict__ cw3,
                         const short* __restrict__ csg, const short* __restrict__ csu,
                         short* __restrict__ hbE, short* __restrict__ hbS,
                         const int* __restrict__ counts, const int* __restrict__ offsets,
                         const int* __restrict__ meta) {
  const int tid = threadIdx.x;
  __shared__ int spre[17];
  __shared__ __align__(16) char pool[49152];
  short (*Ab)[128][32] = (short(*)[128][32])pool;             // [2][128][32]  16KB
  short (*Bb)[128][32] = (short(*)[128][32])(pool + 16384);   // [4][G64|U64][32] 32KB
  float* scratch = (float*)pool;                              // 32KB, epilogue only

  if (tid < 17) spre[tid] = meta[tid];
  __syncthreads();
  const int expertT = spre[16] * 26;
  const int xcd = blockIdx.x & 7;
  const int lb  = blockIdx.x >> 3;          // 0..95
  const int eChunk = (expertT + 7) >> 3;
  const int eBase = xcd * eChunk;
  int eMine = expertT - eBase;
  if (eMine < 0) eMine = 0;
  if (eMine > eChunk) eMine = eChunk;
  const int myTotal = 104 + eMine;          // 104 shared (832/8) + expert share

  const int lane = tid & 63;
  const int w = tid >> 6;
  const int wmv = (w & 1) * 64;     // m-half
  const int mat = w >> 1;           // 0=G, 1=U
  const int lrow = lane & 15;
  const int lkg = lane >> 4;
  const int a_ko = (tid & 3) << 3;

  for (int l = lb; l < myTotal; l += 96) {
    const short* A; const short* b1tile; const short* b3tile; short* H;
    int N, mtile, ntile, rowbase = 0, cnt = 0x7fffffff;
    bool expert;
    if (l >= 104) {
      const int ticket = eBase + (l - 104);
      const int p = ticket / 26;
      const int n = ticket % 26;
      int e = 0;
#pragma unroll
      for (int i = 1; i < 16; ++i) if (p >= spre[i]) e = i;
      const int m = p - spre[e];
      cnt = counts[e];
      rowbase = offsets[e];
      mtile = m * 128;
      A = xg;
      b1tile = cw1 + ((size_t)((e * 26 + n) * 80)) * 2048;
      b3tile = cw3 + ((size_t)((e * 26 + n) * 80)) * 2048;
      H = hbE; N = IDIM; ntile = n * 64; expert = true;
    } else {
      const int s = xcd * 104 + l;    // 0..831
      const int n = s % 52;
      const int m = s / 52;           // 0..15
      mtile = m * 128;
      A = xb;
      b1tile = csg + ((size_t)(n * 80)) * 2048;
      b3tile = csu + ((size_t)(n * 80)) * 2048;
      H = hbS; N = ISDIM; ntile = n * 64; expert = false;
    }
    const int K = HDIM;
    const int KT = HDIM / 32;         // 80

    f32x4 acc[4][4];
#pragma unroll
    for (int i = 0; i < 4; ++i)
#pragma unroll
      for (int j = 0; j < 4; ++j) { f32x4 z = {0.f,0.f,0.f,0.f}; acc[i][j] = z; }

    int gr0, gr1;
    {
      int r0 = tid >> 2, r1 = (tid >> 2) + 64;
      gr0 = expert ? (rowbase + mtile + r0) : (mtile + r0);
      gr1 = expert ? (rowbase + mtile + r1) : (mtile + r1);
      if (gr0 > NPAIR - 1) gr0 = NPAIR - 1;
      if (gr1 > NPAIR - 1) gr1 = NPAIR - 1;
    }
    const short* a_src0 = A + (size_t)gr0 * K + a_ko;
    const short* a_src1 = A + (size_t)gr1 * K + a_ko;

#define STAGEA_U(kt) do { \
    GLDS16(a_src0 + ((kt) << 5), (short*)Ab[(kt) & 1] + tid * 8); \
    GLDS16(a_src1 + ((kt) << 5), (short*)Ab[(kt) & 1] + (tid + 256) * 8); \
  } while (0)
#define STAGEB_U(kt) do { \
    GLDS16(b1tile + (size_t)(kt) * 2048 + tid * 8, (short*)Bb[(kt) & 3] + tid * 8); \
    GLDS16(b3tile + (size_t)(kt) * 2048 + tid * 8, (short*)Bb[(kt) & 3] + 2048 + tid * 8); \
  } while (0)

    auto compute = [&](int ab, int bb) {
      bf16x8 af[4], bfv[4];
#pragma unroll
      for (int mf = 0; mf < 4; ++mf)
        af[mf] = *reinterpret_cast<const bf16x8*>(&Ab[ab][wmv + mf * 16 + lrow][lkg << 3]);
#pragma unroll
      for (int nf = 0; nf < 4; ++nf) {
        const int nloc = nf * 16 + lrow;
        const int kg = (lkg ^ ((nloc >> 1) & 3)) << 3;
        bfv[nf] = *reinterpret_cast<const bf16x8*>(&Bb[bb][mat * 64 + nloc][kg]);
      }
      __builtin_amdgcn_s_setprio(1);
#pragma unroll
      for (int mf = 0; mf < 4; ++mf)
#pragma unroll
        for (int nf = 0; nf < 4; ++nf)
          acc[mf][nf] = __builtin_amdgcn_mfma_f32_16x16x32_bf16(af[mf], bfv[nf], acc[mf][nf], 0, 0, 0);
      __builtin_amdgcn_s_setprio(0);
    };

    // prologue: A(0) first, then B(0..2) -> wait newest-needed B(0): VMCNT(4)
    STAGEA_U(0);
    STAGEB_U(0); STAGEB_U(1); STAGEB_U(2);
    VMCNT(4);
    LGKM_BAR();
    for (int i = 0; i < KT; ++i) {
      if (i) {
        if (i + 2 < KT) { VMCNT(2); } else { VMCNT(0); }
        LGKM_BAR();
      }
      if (i + 1 < KT) STAGEA_U(i + 1);
      if (i + 3 < KT) STAGEB_U(i + 3);
      compute(i & 1, i & 3);
    }
    LGKM_BAR();   // all compute reads done before scratch writes

    // epilogue: U-waves export acc to scratch; G-waves fuse silu(g)*u -> H.
    if (mat) {
      float* sc = scratch + (size_t)(w & 1) * 4096;
#pragma unroll
      for (int mf = 0; mf < 4; ++mf)
#pragma unroll
        for (int r = 0; r < 4; ++r) {
          const int row = mf * 16 + ((lane >> 4) << 2) + r;
#pragma unroll
          for (int nf = 0; nf < 4; ++nf)
            sc[row * 64 + nf * 16 + lrow] = acc[mf][nf][r];
        }
    }
    LGKM_BAR();
    if (!mat) {
      const float* sc = scratch + (size_t)(w & 1) * 4096;
#pragma unroll
      for (int mf = 0; mf < 4; ++mf) {
#pragma unroll
        for (int r = 0; r < 4; ++r) {
          const int row = mf * 16 + ((lane >> 4) << 2) + r;
          const int rt = wmv + row;
          if (expert && mtile + rt >= cnt) continue;
          const size_t grow = (size_t)((expert ? rowbase : 0) + mtile + rt);
          const int colb = ntile + lrow;
#pragma unroll
          for (int nf = 0; nf < 4; ++nf) {
            float g = acc[mf][nf][r];
            float u = sc[row * 64 + nf * 16 + lrow];
            H[grow * N + colb + nf * 16] = f2bf(g / (1.f + expf(-g)) * u);
          }
        }
      }
    }
    LGKM_BAR();   // scratch reads complete before next ticket's staging
#undef STAGEA_U
#undef STAGEB_U
  }
}

// ================= merged DOWN (persistent, 256 thr = 4 waves): Out = A*B.
// Block tile 128m x 128n; wave tile 64x64.  R16-best asym pipeline.
// XCD-chunked tickets; each chunk gets exactly 40 shared (long) tiles first.
__launch_bounds__(256, 3)
__global__ void moe_dn_k(const short* __restrict__ hbE, const short* __restrict__ hbS,
                         const short* __restrict__ cw2, const short* __restrict__ csd,
                         float* __restrict__ pairs, float* __restrict__ outb,
                         const int* __restrict__ counts, const int* __restrict__ offsets,
                         const float* __restrict__ wrow, const int* __restrict__ meta) {
  const int tid = threadIdx.x;
  __shared__ int spre[17];
  __shared__ short Ab[2][128][32];   // 16 KB, linear
  __shared__ short Bb[4][128][32];   // 32 KB, swizzled [n][k] tile-linear

  if (tid < 17) spre[tid] = meta[tid];
  __syncthreads();
  const int expertT = spre[16] * 20;
  const int xcd = blockIdx.x & 7;
  const int lb  = blockIdx.x >> 3;          // 0..95
  const int eChunk = (expertT + 7) >> 3;
  const int eBase = xcd * eChunk;
  int eMine = expertT - eBase;
  if (eMine < 0) eMine = 0;
  if (eMine > eChunk) eMine = eChunk;
  const int myTotal = 40 + eMine;           // 40 shared (320/8) + expert share

  const int lane = tid & 63;
  const int w = tid >> 6;
  const int wm = (w >> 1) * 64;
  const int wn = (w & 1) * 64;
  const int lrow = lane & 15;
  const int lkg = lane >> 4;
  const int a_ko = (tid & 3) << 3;

  for (int l = lb; l < myTotal; l += 96) {
    const short* A; const short* btile; float* Out;
    int K, KT, mtile, ntile, rowbase = 0, cnt = 0x7fffffff;
    bool expert;
    if (l < 40) {                     // shared first (long tiles, KT=104)
      const int s = xcd * 40 + l;     // 0..319
      const int n = s % 20;
      const int m = s / 20;           // 0..15
      mtile = m * 128;
      A = hbS;
      btile = csd + ((size_t)(n * 104)) * 4096;
      Out = outb; K = ISDIM; KT = ISDIM / 32; ntile = n * 128; expert = false;
    } else {
      const int te = eBase + (l - 40);
      const int p = te / 20;
      const int n = te % 20;
      int e = 0;
#pragma unroll
      for (int i = 1; i < 16; ++i) if (p >= spre[i]) e = i;
      const int m = p - spre[e];
      cnt = counts[e];
      rowbase = offsets[e];
      mtile = m * 128;
      A = hbE;
      btile = cw2 + ((size_t)((e * 20 + n) * 52)) * 4096;
      Out = pairs; K = IDIM; KT = IDIM / 32; ntile = n * 128; expert = true;   // KT=52
    }

    f32x4 acc[4][4];
#pragma unroll
    for (int i = 0; i < 4; ++i)
#pragma unroll
      for (int j = 0; j < 4; ++j) { f32x4 z = {0.f,0.f,0.f,0.f}; acc[i][j] = z; }

    int gr0, gr1;
    {
      int r0 = tid >> 2, r1 = (tid >> 2) + 64;
      gr0 = expert ? (rowbase + mtile + r0) : (mtile + r0);
      gr1 = expert ? (rowbase + mtile + r1) : (mtile + r1);
      if (gr0 > NPAIR - 1) gr0 = NPAIR - 1;
      if (gr1 > NPAIR - 1) gr1 = NPAIR - 1;
    }
    const short* a_src0 = A + (size_t)gr0 * K + a_ko;
    const short* a_src1 = A + (size_t)gr1 * K + a_ko;

#define STAGEA_D(kt) do { \
    GLDS16(a_src0 + ((kt) << 5), (short*)Ab[(kt) & 1] + tid * 8); \
    GLDS16(a_src1 + ((kt) << 5), (short*)Ab[(kt) & 1] + (tid + 256) * 8); \
  } while (0)
#define STAGEB_D(kt) do { \
    GLDS16(btile + (size_t)(kt) * 4096 + tid * 8, (short*)Bb[(kt) & 3] + tid * 8); \
    GLDS16(btile + (size_t)(kt) * 4096 + (tid + 256) * 8, (short*)Bb[(kt) & 3] + (tid + 256) * 8); \
  } while (0)

    auto compute = [&](int ab, int bb) {
      bf16x8 af[4], bfv[4];
#pragma unroll
      for (int mf = 0; mf < 4; ++mf)
        af[mf] = *reinterpret_cast<const bf16x8*>(&Ab[ab][wm + mf * 16 + lrow][lkg << 3]);
#pragma unroll
      for (int nf = 0; nf < 4; ++nf) {
        const int n = wn + nf * 16 + lrow;
        const int kg = (lkg ^ ((n >> 1) & 3)) << 3;
        bfv[nf] = *reinterpret_cast<const bf16x8*>(&Bb[bb][n][kg]);
      }
      __builtin_amdgcn_s_setprio(1);
#pragma unroll
      for (int mf = 0; mf < 4; ++mf)
#pragma unroll
        for (int nf = 0; nf < 4; ++nf)
          acc[mf][nf] = __builtin_amdgcn_mfma_f32_16x16x32_bf16(af[mf], bfv[nf], acc[mf][nf], 0, 0, 0);
      __builtin_amdgcn_s_setprio(0);
    };

    STAGEA_D(0);
    STAGEB_D(0); STAGEB_D(1); STAGEB_D(2);
    VMCNT(4);
    LGKM_BAR();
    for (int i = 0; i < KT; ++i) {
      if (i) {
        if (i + 2 < KT) { VMCNT(2); } else { VMCNT(0); }
        LGKM_BAR();
      }
      if (i + 1 < KT) STAGEA_D(i + 1);
      if (i + 3 < KT) STAGEB_D(i + 3);
      compute(i & 1, i & 3);
    }

#pragma unroll
    for (int mf = 0; mf < 4; ++mf) {
#pragma unroll
      for (int r = 0; r < 4; ++r) {
        const int rt = wm + mf * 16 + ((lane >> 4) << 2) + r;
        const int colb = ntile + wn + lrow;
        if (expert) {
          if (mtile + rt < cnt) {
            const int gr = rowbase + mtile + rt;
            const float sc = wrow[gr];
            float* o = Out + (size_t)gr * HDIM + colb;
#pragma unroll
            for (int nf = 0; nf < 4; ++nf) o[nf * 16] = sc * acc[mf][nf][r];
          }
        } else {
          float* o = Out + (size_t)(mtile + rt) * HDIM + colb;
#pragma unroll
          for (int nf = 0; nf < 4; ++nf) o[nf * 16] = acc[mf][nf][r];
        }
      }
    }
    LGKM_BAR();   // final compute reads complete before next ticket's staging
#undef STAGEA_D
#undef STAGEB_D
  }
}

// ---------------- final combine: out[t] += pairs[g0] + pairs[g1]
__global__ void combine_kernel(float* __restrict__ out, const float* __restrict__ pairs,
                               const int* __restrict__ pairpos) {
  const int t = blockIdx.x;
  const int g0 = pairpos[t * 2], g1 = pairpos[t * 2 + 1];
  const f32x4* p0 = (const f32x4*)(pairs + (size_t)g0 * HDIM);
  const f32x4* p1 = (const f32x4*)(pairs + (size_t)g1 * HDIM);
  f32x4* o = (f32x4*)(out + (size_t)t * HDIM);
  for (int c = threadIdx.x; c < HDIM / 4; c += 256)
    o[c] = o[c] + p0[c] + p1[c];
}

extern "C" void kernel_launch(void* const* d_in, const int* in_sizes, int n_in,
                              void* d_out, int out_size, void* d_ws, size_t ws_size,
                              hipStream_t stream) {
  const float* x  = (const float*)d_in[0];
  const float* rw = (const float*)d_in[1];
  const float* w1 = (const float*)d_in[2];
  const float* w3 = (const float*)d_in[3];
  const float* w2 = (const float*)d_in[4];
  const float* sg = (const float*)d_in[5];
  const float* su = (const float*)d_in[6];
  const float* sd = (const float*)d_in[7];
  float* out = (float*)d_out;
  (void)in_sizes; (void)n_in; (void)out_size; (void)ws_size;

  char* ws = (char*)d_ws;
  size_t off = 0;
  auto alloc = [&](size_t bytes) -> void* {
    void* p = ws + off;
    off = (off + bytes + 255) & ~(size_t)255;
    return p;
  };
  int*   counts  = (int*)alloc(NEXP * 4);          // @0
  int*   slotc   = (int*)alloc(NEXP * 4);          // @256
  int*   offsets = (int*)alloc(NEXP * 4);
  int*   meta    = (int*)alloc(32 * 4);
  int*   tidx    = (int*)alloc(NPAIR * 4);
  float* tw      = (float*)alloc(NPAIR * 4);
  float* wrowv   = (float*)alloc(NPAIR * 4);
  int*   pairpos = (int*)alloc(NPAIR * 4);
  short* xb      = (short*)alloc((size_t)TOKENS * HDIM * 2);
  short* xg      = (short*)alloc((size_t)NPAIR * HDIM * 2);
  short* hbE     = (short*)alloc((size_t)NPAIR * IDIM * 2);
  short* hbS     = (short*)alloc((size_t)TOKENS * ISDIM * 2);
  float* pairs   = (float*)alloc((size_t)NPAIR * HDIM * 4);
  // converted-weight regions (phase-reused): cwA holds w1' then w2'; cwS1 sg' then sd'
  short* cwA  = (short*)alloc((size_t)NEXP * HDIM * IDIM * 2);   // 136.3 MB
  short* cwB  = (short*)alloc((size_t)NEXP * HDIM * IDIM * 2);   // 136.3 MB
  short* cwS1 = (short*)alloc((size_t)HDIM * ISDIM * 2);         // 17.0 MB
  short* cwS2 = (short*)alloc((size_t)HDIM * ISDIM * 2);         // 17.0 MB

  hipMemsetAsync(d_ws, 0, 512, stream);  // zero counts + slotc

  router_kernel<<<dim3(TOKENS), dim3(64), 0, stream>>>(x, rw, counts, tidx, tw);
  scan_kernel<<<dim3(1), dim3(64), 0, stream>>>(counts, offsets, meta);
  gather_kernel<<<dim3(TOKENS), dim3(256), 0, stream>>>(x, tidx, tw, offsets, slotc,
                                                        pairpos, wrowv, xb, xg);

  // convert up-phase weights (coalesced LDS-transpose)
  wconv2_kernel<64><<<dim3(NEXP * 26 * 80), dim3(256), 0, stream>>>(w1, cwA, HDIM, IDIM, 26, 80);
  wconv2_kernel<64><<<dim3(NEXP * 26 * 80), dim3(256), 0, stream>>>(w3, cwB, HDIM, IDIM, 26, 80);
  wconv2_kernel<64><<<dim3(52 * 80), dim3(256), 0, stream>>>(sg, cwS1, HDIM, ISDIM, 52, 80);
  wconv2_kernel<64><<<dim3(52 * 80), dim3(256), 0, stream>>>(su, cwS2, HDIM, ISDIM, 52, 80);

  // merged up: persistent 768 blocks, XCD-chunked tickets
  moe_up_k<<<dim3(NPERS), dim3(256), 0, stream>>>(
      xg, xb, cwA, cwB, cwS1, cwS2, hbE, hbS, counts, offsets, meta);

  // convert down-phase weights into the freed regions
  wconv2_kernel<128><<<dim3(NEXP * 20 * 52), dim3(256), 0, stream>>>(w2, cwA, IDIM, HDIM, 20, 52);
  wconv2_kernel<128><<<dim3(20 * 104), dim3(256), 0, stream>>>(sd, cwS1, ISDIM, HDIM, 20, 104);

  // merged down: persistent 768 blocks, XCD-chunked tickets
  moe_dn_k<<<dim3(NPERS), dim3(256), 0, stream>>>(
      hbE, hbS, cwA, cwS1, pairs, out, counts, offsets, wrowv, meta);

  combine_kernel<<<dim3(TOKENS), dim3(256), 0, stream>>>(out, pairs, pairpos);
}